// Round 1
// 422.411 us; speedup vs baseline: 1.0995x; 1.0995x over previous
//
#include <hip/hip_runtime.h>

// Problem constants: BOX=256, OS=1 -> S=256, NC=10, B=16, N=262144
#define S_     256
#define NC_    10
#define CHUNK  2048         // points per staging block (was 4096)
#define NBIN   256          // 16x16 tiles of 16x16 px per batch
#define CAP    1536         // max records staged in LDS per tile (~16 sigma)
#define RSTR   7            // k_fused LDS record stride in u32 (padded)

typedef unsigned int u32;

__device__ __forceinline__ u32 f2bf(float f) {          // f32 -> bf16 (RNE)
    u32 u = __float_as_uint(f);
    return (u + 0x7fffu + ((u >> 16) & 1u)) >> 16;
}
__device__ __forceinline__ float bf2f(u32 h) { return __uint_as_float(h << 16); }

// Record (24 B, 3x uint2): w0 = qx | qy<<16 (tile-local coords, fp 1/2048 px,
// qx in [0,32767]); w1..w5 = 10 bf16 values. cell-in-tile = (qy>>11)*16+(qx>>11).

// ---- K1: per-chunk histogram over the 256 16px-tiles of its batch ----
__global__ void __launch_bounds__(256)
k_hist(const float* __restrict__ points, u32* __restrict__ hist, int N) {
    __shared__ u32 h[NBIN];
    h[threadIdx.x] = 0;
    __syncthreads();
    const int cpb = N / CHUNK;
    const int b  = blockIdx.x / cpb;
    const int n0 = (blockIdx.x % cpb) * CHUNK;
    const float* pb = points + (size_t)b * 2 * N;
    for (int i = threadIdx.x; i < CHUNK; i += 256) {
        int n = n0 + i;
        float px = (pb[n] + 0.5f) * (float)S_;
        float py = (pb[(size_t)N + n] + 0.5f) * (float)S_;
        int xi = (int)floorf(px), yi = (int)floorf(py);
        int bin = ((yi >> 4) << 4) + (xi >> 4);
        atomicAdd(&h[bin], 1u);
    }
    __syncthreads();
    hist[(size_t)blockIdx.x * NBIN + threadIdx.x] = h[threadIdx.x];
}

// ---- K2: one block per batch; scan 256 bins, emit bases + per-chunk cursors ----
__global__ void __launch_bounds__(256)
k_scan(const u32* __restrict__ hist, u32* __restrict__ blockStart,
       u32* __restrict__ binBase, u32* __restrict__ binCnt, int cpb, int N) {
    __shared__ u32 s[256];
    const int b = blockIdx.x, t = threadIdx.x;
    u32 tot = 0;
    for (int i = 0; i < cpb; ++i) tot += hist[(size_t)(b * cpb + i) * NBIN + t];
    s[t] = tot;
    __syncthreads();
    for (int off = 1; off < 256; off <<= 1) {
        u32 y = (t >= off) ? s[t - off] : 0;
        __syncthreads();
        s[t] += y;
        __syncthreads();
    }
    u32 base = (u32)b * (u32)N + s[t] - tot;             // batch-major layout
    binBase[b * NBIN + t] = base;
    binCnt[b * NBIN + t]  = tot;
    u32 run = base;
    for (int i = 0; i < cpb; ++i) {
        size_t idx = (size_t)(b * cpb + i) * NBIN + t;
        u32 hv = hist[idx];
        blockStart[idx] = run;
        run += hv;
    }
}

// ---- K3: in-LDS counting sort per chunk, then coalesced record flush ----
// Old version did 3x8B stores per record at atomic-scattered addresses ->
// WRITE_SIZE 187 MB vs 100.7 MB ideal (1.86x partial-line amplification).
// Now: sort the chunk's records by bin in LDS; each bin's run is contiguous
// in global (blockStart ownership), so the flush is a linear LDS->global copy
// with consecutive lanes writing consecutive uint2s.
__global__ void __launch_bounds__(256)
k_scatter(const float* __restrict__ points, const float* __restrict__ values,
          const u32* __restrict__ blockStart, uint2* __restrict__ recs, int N) {
    __shared__ u32 cnt[NBIN];           // histogram -> cursor
    __shared__ u32 sc[NBIN];            // scan scratch
    __shared__ u32 gOff[NBIN];          // blockStart[bin] - excl[bin]
    __shared__ u32 recDst[CHUNK];       // global record index per sorted slot
    __shared__ uint2 lrec[CHUNK * 3];   // 48 KB sorted records

    const int tid = threadIdx.x;
    const int cpb = N / CHUNK;
    const int b  = blockIdx.x / cpb;
    const int n0 = (blockIdx.x % cpb) * CHUNK;
    const float* pb = points + (size_t)b * 2 * N;
    const float* vb = values + (size_t)b * NC_ * N;

    cnt[tid] = 0;
    __syncthreads();

    // phase 1: load points, quantize, per-block bin histogram
    const int PPT = CHUNK / 256;        // 8 points per thread
    u32 w0[PPT];
    u32 binArr[PPT];
#pragma unroll
    for (int k = 0; k < PPT; ++k) {
        int n = n0 + tid + k * 256;
        float px = (pb[n] + 0.5f) * (float)S_;
        float py = (pb[(size_t)N + n] + 0.5f) * (float)S_;
        int xi = (int)floorf(px), yi = (int)floorf(py);
        u32 qx = __float2uint_rn((px - (float)(xi & ~15)) * 2048.0f);
        u32 qy = __float2uint_rn((py - (float)(yi & ~15)) * 2048.0f);
        qx = min(qx, 32767u); qy = min(qy, 32767u);
        w0[k] = qx | (qy << 16);
        binArr[k] = (u32)(((yi >> 4) << 4) + (xi >> 4));
        atomicAdd(&cnt[binArr[k]], 1u);
    }
    __syncthreads();

    // phase 2: exclusive scan of bin counts; compute global offset per bin
    u32 c = cnt[tid];
    sc[tid] = c;
    __syncthreads();
    for (int off = 1; off < 256; off <<= 1) {
        u32 y = (tid >= off) ? sc[tid - off] : 0;
        __syncthreads();
        sc[tid] += y;
        __syncthreads();
    }
    u32 excl = sc[tid] - c;
    gOff[tid] = blockStart[(size_t)blockIdx.x * NBIN + tid] - excl;
    __syncthreads();
    cnt[tid] = excl;                     // becomes the scatter cursor
    __syncthreads();

    // phase 3: load values, build records, scatter into LDS in bin order
#pragma unroll
    for (int k = 0; k < PPT; ++k) {
        int n = n0 + tid + k * 256;
        float v[NC_];
#pragma unroll
        for (int cc = 0; cc < NC_; ++cc) v[cc] = vb[(size_t)cc * N + n];
        u32 bin = binArr[k];
        u32 slot = atomicAdd(&cnt[bin], 1u);
        recDst[slot] = gOff[bin] + slot;
        lrec[slot * 3]     = make_uint2(w0[k],
                                        f2bf(v[0]) | (f2bf(v[1]) << 16));
        lrec[slot * 3 + 1] = make_uint2(f2bf(v[2]) | (f2bf(v[3]) << 16),
                                        f2bf(v[4]) | (f2bf(v[5]) << 16));
        lrec[slot * 3 + 2] = make_uint2(f2bf(v[6]) | (f2bf(v[7]) << 16),
                                        f2bf(v[8]) | (f2bf(v[9]) << 16));
    }
    __syncthreads();

    // phase 4: coalesced flush (uint2 granularity). Consecutive lanes hold
    // consecutive sorted words -> consecutive global addresses within a run.
    for (int p = tid; p < CHUNK * 3; p += 256) {
        u32 r = (u32)p / 3u;             // magic-mul, compile-time const
        u32 cidx = (u32)p - r * 3u;
        recs[(size_t)recDst[r] * 3u + cidx] = lrec[p];
    }
}

// ---- K4 fused: in-LDS cell sort + register gather, one block per tile ----
// Writes 15x15 interior pixels (full sums) with plain stores; 17x17 border
// partials go to borderBuf for k_border to combine. No global atomics.
__global__ void __launch_bounds__(256)
k_fused(const uint2* __restrict__ recs, const u32* __restrict__ binBase,
        const u32* __restrict__ binCnt, float* __restrict__ out,
        float* __restrict__ borderBuf) {
    __shared__ u32 cnt[NBIN];          // histogram -> cursor -> cell end
    __shared__ u32 excl[NBIN];         // cell start
    __shared__ u32 sc[NBIN];           // scan scratch
    __shared__ u32 lrec[CAP * RSTR];   // 43 KB cell-sorted records

    const int tid = threadIdx.x;
    const int g = blockIdx.x;                       // batch*256 + tile
    const int batch = g >> 8, t = g & 255;
    const int ox = (t & 15) * 16, oy = (t >> 4) * 16;
    const u32 base = binBase[g];
    const u32 n = min(binCnt[g], (u32)CAP);         // overflow -> k_cleanup

    cnt[tid] = 0;
    __syncthreads();

    // phase a: stage segment into registers + cell histogram
    u32 r[6][6];
    int cell[6];
#pragma unroll
    for (int k = 0; k < 6; ++k) {
        int i = k * 256 + tid;
        cell[k] = -1;
        if (i < (int)n) {
            size_t sa = (size_t)(base + i) * 3;
            uint2 a = recs[sa], b2 = recs[sa + 1], c2 = recs[sa + 2];
            r[k][0] = a.x;  r[k][1] = a.y;
            r[k][2] = b2.x; r[k][3] = b2.y;
            r[k][4] = c2.x; r[k][5] = c2.y;
            u32 qx = a.x & 0xffffu, qy = a.x >> 16;
            cell[k] = (int)(((qy >> 11) << 4) | (qx >> 11));
            atomicAdd(&cnt[cell[k]], 1u);
        }
    }
    __syncthreads();

    // phase b: exclusive scan of 256 cell counts
    u32 c = cnt[tid];
    sc[tid] = c;
    __syncthreads();
    for (int off = 1; off < 256; off <<= 1) {
        u32 y = (tid >= off) ? sc[tid - off] : 0;
        __syncthreads();
        sc[tid] += y;
        __syncthreads();
    }
    excl[tid] = sc[tid] - c;
    __syncthreads();
    cnt[tid] = excl[tid];                            // cursor
    __syncthreads();

    // phase c: scatter registers into LDS in cell order
#pragma unroll
    for (int k = 0; k < 6; ++k) {
        if (cell[k] >= 0) {
            u32 o = atomicAdd(&cnt[cell[k]], 1u) * RSTR;
#pragma unroll
            for (int w = 0; w < 6; ++w) lrec[o + w] = r[k][w];
        }
    }
    __syncthreads();                                 // cnt[c] is now cell end

    // phase d: gather 17x17 pixel partials from LDS
    for (int p = tid; p < 289; p += 256) {
        int lx = p % 17, ly = p / 17;
        float acc[NC_];
#pragma unroll
        for (int q = 0; q < NC_; ++q) acc[q] = 0.0f;
#pragma unroll
        for (int dy = 0; dy < 2; ++dy) {
            int cy = ly - 1 + dy;                    // dy=1 -> own cell (w=1-ry)
            if ((unsigned)cy >= 16u) continue;
#pragma unroll
            for (int dx = 0; dx < 2; ++dx) {
                int cx = lx - 1 + dx;
                if ((unsigned)cx >= 16u) continue;
                int cc = (cy << 4) | cx;
                u32 j1 = cnt[cc];
                for (u32 j = excl[cc]; j < j1; ++j) {
                    u32 o = j * RSTR;
                    u32 w0 = lrec[o];
                    float rx = (float)(w0 & 2047u)         * (1.0f / 2048.0f);
                    float ry = (float)((w0 >> 16) & 2047u) * (1.0f / 2048.0f);
                    float w = (dx ? (1.0f - rx) : rx) * (dy ? (1.0f - ry) : ry);
                    u32 w1 = lrec[o + 1], w2 = lrec[o + 2], w3 = lrec[o + 3],
                        w4 = lrec[o + 4], w5 = lrec[o + 5];
                    acc[0] += w * bf2f(w1 & 0xffffu); acc[1] += w * bf2f(w1 >> 16);
                    acc[2] += w * bf2f(w2 & 0xffffu); acc[3] += w * bf2f(w2 >> 16);
                    acc[4] += w * bf2f(w3 & 0xffffu); acc[5] += w * bf2f(w3 >> 16);
                    acc[6] += w * bf2f(w4 & 0xffffu); acc[7] += w * bf2f(w4 >> 16);
                    acc[8] += w * bf2f(w5 & 0xffffu); acc[9] += w * bf2f(w5 >> 16);
                }
            }
        }
        bool interior = (lx >= 1) & (lx <= 15) & (ly >= 1) & (ly <= 15);
        if (interior) {
            int gx = ox + lx, gy = oy + ly;
            float* ob = out + (size_t)batch * NC_ * S_ * S_ + gy * S_ + gx;
#pragma unroll
            for (int q = 0; q < NC_; ++q) ob[(size_t)q * S_ * S_] = acc[q];
        } else {
            float* bb = borderBuf + ((size_t)g * 289 + p) * NC_;
#pragma unroll
            for (int q = 0; q < NC_; ++q) bb[q] = acc[q];
        }
    }
}

// ---- K5: combine border partials (<=2x2 tiles per border pixel) ----
__global__ void __launch_bounds__(256)
k_border(const float* __restrict__ borderBuf, float* __restrict__ out) {
    int idx = blockIdx.x * 256 + threadIdx.x;        // b*65536 + gy*256 + gx
    int b = idx >> 16, rem = idx & 65535;
    int gy = rem >> 8, gx = rem & 255;
    bool bx = (gx & 15) == 0, by = (gy & 15) == 0;
    if (!bx && !by) return;

    int txs[2], lxs[2], nx = 0;
    if (bx) {
        if (gx > 0) { txs[nx] = (gx >> 4) - 1; lxs[nx] = 16; ++nx; }
        txs[nx] = gx >> 4; lxs[nx] = 0; ++nx;
    } else { txs[0] = gx >> 4; lxs[0] = gx & 15; nx = 1; }
    int tys[2], lys[2], ny = 0;
    if (by) {
        if (gy > 0) { tys[ny] = (gy >> 4) - 1; lys[ny] = 16; ++ny; }
        tys[ny] = gy >> 4; lys[ny] = 0; ++ny;
    } else { tys[0] = gy >> 4; lys[0] = gy & 15; ny = 1; }

    float acc[NC_];
#pragma unroll
    for (int q = 0; q < NC_; ++q) acc[q] = 0.0f;
    for (int j = 0; j < ny; ++j)
        for (int i = 0; i < nx; ++i) {
            int g = (b << 8) + (tys[j] << 4) + txs[i];
            int p = lys[j] * 17 + lxs[i];
            const float* bb = borderBuf + ((size_t)g * 289 + p) * NC_;
#pragma unroll
            for (int q = 0; q < NC_; ++q) acc[q] += bb[q];
        }
    float* ob = out + (size_t)b * NC_ * S_ * S_ + gy * S_ + gx;
#pragma unroll
    for (int q = 0; q < NC_; ++q) ob[(size_t)q * S_ * S_] = acc[q];
}

// ---- K6: overflow cleanup (normally a no-op; strict correctness) ----
__global__ void __launch_bounds__(256)
k_cleanup(const uint2* __restrict__ recs, const u32* __restrict__ binBase,
          const u32* __restrict__ binCnt, float* __restrict__ out, int nTiles) {
    int g = blockIdx.x * 256 + threadIdx.x;
    if (g >= nTiles) return;
    u32 n = binCnt[g];
    if (n <= (u32)CAP) return;
    int batch = g >> 8, t = g & 255;
    int ox = (t & 15) * 16, oy = (t >> 4) * 16;
    u32 base = binBase[g];
    float* ob = out + (size_t)batch * NC_ * S_ * S_;
    for (u32 i = CAP; i < n; ++i) {
        size_t sa = (size_t)(base + i) * 3;
        uint2 a = recs[sa], b2 = recs[sa + 1], c2 = recs[sa + 2];
        u32 qx = a.x & 0xffffu, qy = a.x >> 16;
        int xi = ox + (int)(qx >> 11), yi = oy + (int)(qy >> 11);
        float rx = (float)(qx & 2047u) * (1.0f / 2048.0f);
        float ry = (float)(qy & 2047u) * (1.0f / 2048.0f);
        float v[NC_];
        v[0] = bf2f(a.y & 0xffffu);  v[1] = bf2f(a.y >> 16);
        v[2] = bf2f(b2.x & 0xffffu); v[3] = bf2f(b2.x >> 16);
        v[4] = bf2f(b2.y & 0xffffu); v[5] = bf2f(b2.y >> 16);
        v[6] = bf2f(c2.x & 0xffffu); v[7] = bf2f(c2.x >> 16);
        v[8] = bf2f(c2.y & 0xffffu); v[9] = bf2f(c2.y >> 16);
        for (int dx = 0; dx < 2; ++dx) {
            int x_ = xi + dx; if (x_ >= S_) continue;
            float wx = dx ? rx : (1.0f - rx);
            for (int dy = 0; dy < 2; ++dy) {
                int y_ = yi + dy; if (y_ >= S_) continue;
                float w = wx * (dy ? ry : (1.0f - ry));
                for (int c = 0; c < NC_; ++c)
                    atomicAdd(ob + (size_t)c * S_ * S_ + y_ * S_ + x_, w * v[c]);
            }
        }
    }
}

// ---- fallback: direct atomic scatter (any shape) ----
__global__ void __launch_bounds__(256)
scatter_cic_kernel(const float* __restrict__ points,
                   const float* __restrict__ values,
                   float* __restrict__ out, int N) {
    const int n = blockIdx.x * blockDim.x + threadIdx.x;
    const int b = blockIdx.y;
    if (n >= N) return;
    const float* pb = points + (size_t)b * 2 * N;
    const float px = (pb[n] + 0.5f) * (float)S_;
    const float py = (pb[(size_t)N + n] + 0.5f) * (float)S_;
    const float xf = floorf(px), yf = floorf(py);
    const float rx = px - xf, ry = py - yf;
    const int xi = (int)xf, yi = (int)yf;
    const float* vb = values + (size_t)b * NC_ * N + n;
    float v[NC_];
#pragma unroll
    for (int c = 0; c < NC_; ++c) v[c] = vb[(size_t)c * N];
    float* ob = out + (size_t)b * NC_ * S_ * S_;
#pragma unroll
    for (int dx = 0; dx < 2; ++dx) {
        const int x_ = xi + dx;
        if (x_ < 0 || x_ >= S_) continue;
        const float wx = dx ? rx : (1.0f - rx);
#pragma unroll
        for (int dy = 0; dy < 2; ++dy) {
            const int y_ = yi + dy;
            if (y_ < 0 || y_ >= S_) continue;
            const float w = wx * (dy ? ry : (1.0f - ry));
            const int idx = y_ * S_ + x_;
#pragma unroll
            for (int c = 0; c < NC_; ++c)
                atomicAdd(ob + (size_t)c * S_ * S_ + idx, w * v[c]);
        }
    }
}

extern "C" void kernel_launch(void* const* d_in, const int* in_sizes, int n_in,
                              void* d_out, int out_size, void* d_ws, size_t ws_size,
                              hipStream_t stream) {
    const float* points = (const float*)d_in[0];   // [B, 2, N]
    const float* values = (const float*)d_in[1];   // [B, NC, N]
    float* out = (float*)d_out;                    // [B, NC, S, S]

    const int B = out_size / (NC_ * S_ * S_);      // 16
    const int N = in_sizes[0] / (2 * B);           // 262144

    const size_t P = (size_t)B * N;
    const int cpb = N / CHUNK;                     // 128
    const int chunksTotal = B * cpb;               // 2048
    const int nTiles = B * NBIN;                   // 4096

    const size_t recBytes    = P * 24;             // 100.7 MB
    const size_t histElems   = (size_t)chunksTotal * NBIN;
    const size_t borderElems = (size_t)nTiles * 289 * NC_;
    const size_t wsNeeded    = recBytes + 2 * histElems * 4 +
                               2 * (size_t)nTiles * 4 + borderElems * 4 + 256;

    const bool fast = (N % CHUNK == 0) && (N >= CHUNK) && (B > 0) &&
                      (P < (1u << 31) / 2) && (ws_size >= wsNeeded);

    if (fast) {
        char* w = (char*)d_ws;
        uint2* recsA     = (uint2*)w;
        u32* hist        = (u32*)(w + recBytes);
        u32* blockStart  = hist + histElems;
        u32* binBase     = blockStart + histElems;
        u32* binCnt      = binBase + nTiles;
        float* borderBuf = (float*)(binCnt + nTiles);

        k_hist<<<chunksTotal, 256, 0, stream>>>(points, hist, N);
        k_scan<<<B, 256, 0, stream>>>(hist, blockStart, binBase, binCnt, cpb, N);
        k_scatter<<<chunksTotal, 256, 0, stream>>>(points, values, blockStart, recsA, N);
        k_fused<<<nTiles, 256, 0, stream>>>(recsA, binBase, binCnt, out, borderBuf);
        k_border<<<(B * 65536) / 256, 256, 0, stream>>>(borderBuf, out);
        k_cleanup<<<(nTiles + 255) / 256, 256, 0, stream>>>(recsA, binBase, binCnt, out, nTiles);
        // every output pixel is written by k_fused (interior) or k_border -> no memset
    } else {
        hipMemsetAsync(d_out, 0, (size_t)out_size * sizeof(float), stream);
        dim3 block(256, 1, 1);
        dim3 grid((N + 255) / 256, B, 1);
        scatter_cic_kernel<<<grid, block, 0, stream>>>(points, values, out, N);
    }
}

// Round 2
// 415.761 us; speedup vs baseline: 1.1171x; 1.0160x over previous
//
#include <hip/hip_runtime.h>

// Problem constants: BOX=256, OS=1 -> S=256, NC=10, B=16, N=262144
#define S_     256
#define NC_    10
#define CHUNK  1024         // points per staging block (28.7 KB LDS -> 5 blocks/CU)
#define NBIN   256          // 16x16 tiles of 16x16 px per batch
#define CAP    1536         // max records staged in LDS per tile (~16 sigma)
#define RSTR   7            // k_fused LDS record stride in u32 (padded)

typedef unsigned int u32;

__device__ __forceinline__ u32 f2bf(float f) {          // f32 -> bf16 (RNE)
    u32 u = __float_as_uint(f);
    return (u + 0x7fffu + ((u >> 16) & 1u)) >> 16;
}
__device__ __forceinline__ float bf2f(u32 h) { return __uint_as_float(h << 16); }

// Record (24 B, 3x uint2): w0 = qx | qy<<16 (tile-local coords, fp 1/2048 px,
// qx in [0,32767]); w1..w5 = 10 bf16 values. cell-in-tile = (qy>>11)*16+(qx>>11).

// ---- K1: per-chunk histogram over the 256 16px-tiles of its batch ----
__global__ void __launch_bounds__(256)
k_hist(const float* __restrict__ points, u32* __restrict__ hist, int N) {
    __shared__ u32 h[NBIN];
    h[threadIdx.x] = 0;
    __syncthreads();
    const int cpb = N / CHUNK;
    const int b  = blockIdx.x / cpb;
    const int n0 = (blockIdx.x % cpb) * CHUNK;
    const float* pb = points + (size_t)b * 2 * N;
    for (int i = threadIdx.x; i < CHUNK; i += 256) {
        int n = n0 + i;
        float px = (pb[n] + 0.5f) * (float)S_;
        float py = (pb[(size_t)N + n] + 0.5f) * (float)S_;
        int xi = (int)floorf(px), yi = (int)floorf(py);
        int bin = ((yi >> 4) << 4) + (xi >> 4);
        atomicAdd(&h[bin], 1u);
    }
    __syncthreads();
    hist[(size_t)blockIdx.x * NBIN + threadIdx.x] = h[threadIdx.x];
}

// ---- K2: one block per batch; scan 256 bins, emit bases + per-chunk cursors ----
__global__ void __launch_bounds__(256)
k_scan(const u32* __restrict__ hist, u32* __restrict__ blockStart,
       u32* __restrict__ binBase, u32* __restrict__ binCnt, int cpb, int N) {
    __shared__ u32 s[256];
    const int b = blockIdx.x, t = threadIdx.x;
    u32 tot = 0;
#pragma unroll 8
    for (int i = 0; i < cpb; ++i) tot += hist[(size_t)(b * cpb + i) * NBIN + t];
    s[t] = tot;
    __syncthreads();
    for (int off = 1; off < 256; off <<= 1) {
        u32 y = (t >= off) ? s[t - off] : 0;
        __syncthreads();
        s[t] += y;
        __syncthreads();
    }
    u32 base = (u32)b * (u32)N + s[t] - tot;             // batch-major layout
    binBase[b * NBIN + t] = base;
    binCnt[b * NBIN + t]  = tot;
    u32 run = base;
#pragma unroll 4
    for (int i = 0; i < cpb; ++i) {
        size_t idx = (size_t)(b * cpb + i) * NBIN + t;
        u32 hv = hist[idx];
        blockStart[idx] = run;
        run += hv;
    }
}

// ---- K3: in-LDS counting sort per chunk, then coalesced record flush ----
// R1 cut WRITE_SIZE 187->110.6 MB (ideal 100.7) but 60 KB LDS capped the
// kernel at 2 blocks/CU (Occupancy 18%, VALUBusy 10%, HBM 26% -> latency
// bound). R2: CHUNK 2048->1024, SoA staging, u8 binId instead of u32 recDst
// -> 28.7 KB LDS -> 5 blocks/CU.
__global__ void __launch_bounds__(256)
k_scatter(const float* __restrict__ points, const float* __restrict__ values,
          const u32* __restrict__ blockStart, uint2* __restrict__ recs, int N) {
    __shared__ u32 cnt[NBIN];           // histogram -> cursor
    __shared__ u32 sc[NBIN];            // scan scratch
    __shared__ u32 gOff[NBIN];          // blockStart[bin] - excl[bin]
    __shared__ unsigned char binId[CHUNK];  // bin of each sorted slot
    __shared__ u32 lw[6][CHUNK];        // 24 KB sorted record words (SoA)

    const int tid = threadIdx.x;
    const int cpb = N / CHUNK;
    const int b  = blockIdx.x / cpb;
    const int n0 = (blockIdx.x % cpb) * CHUNK;
    const float* pb = points + (size_t)b * 2 * N;
    const float* vb = values + (size_t)b * NC_ * N;

    cnt[tid] = 0;
    __syncthreads();

    // phase 1: load points, quantize, per-block bin histogram
    const int PPT = CHUNK / 256;        // 4 points per thread
    u32 w0[PPT];
    u32 binArr[PPT];
#pragma unroll
    for (int k = 0; k < PPT; ++k) {
        int n = n0 + tid + k * 256;
        float px = (pb[n] + 0.5f) * (float)S_;
        float py = (pb[(size_t)N + n] + 0.5f) * (float)S_;
        int xi = (int)floorf(px), yi = (int)floorf(py);
        u32 qx = __float2uint_rn((px - (float)(xi & ~15)) * 2048.0f);
        u32 qy = __float2uint_rn((py - (float)(yi & ~15)) * 2048.0f);
        qx = min(qx, 32767u); qy = min(qy, 32767u);
        w0[k] = qx | (qy << 16);
        binArr[k] = (u32)(((yi >> 4) << 4) + (xi >> 4));
        atomicAdd(&cnt[binArr[k]], 1u);
    }
    __syncthreads();

    // phase 2: exclusive scan of bin counts; compute global offset per bin
    u32 c = cnt[tid];
    sc[tid] = c;
    __syncthreads();
    for (int off = 1; off < 256; off <<= 1) {
        u32 y = (tid >= off) ? sc[tid - off] : 0;
        __syncthreads();
        sc[tid] += y;
        __syncthreads();
    }
    u32 excl = sc[tid] - c;
    gOff[tid] = blockStart[(size_t)blockIdx.x * NBIN + tid] - excl;
    __syncthreads();
    cnt[tid] = excl;                     // becomes the scatter cursor
    __syncthreads();

    // phase 3: load values, build records, scatter into LDS in bin order
#pragma unroll
    for (int k = 0; k < PPT; ++k) {
        int n = n0 + tid + k * 256;
        float v[NC_];
#pragma unroll
        for (int cc = 0; cc < NC_; ++cc) v[cc] = vb[(size_t)cc * N + n];
        u32 bin = binArr[k];
        u32 slot = atomicAdd(&cnt[bin], 1u);
        binId[slot] = (unsigned char)bin;
        lw[0][slot] = w0[k];
        lw[1][slot] = f2bf(v[0]) | (f2bf(v[1]) << 16);
        lw[2][slot] = f2bf(v[2]) | (f2bf(v[3]) << 16);
        lw[3][slot] = f2bf(v[4]) | (f2bf(v[5]) << 16);
        lw[4][slot] = f2bf(v[6]) | (f2bf(v[7]) << 16);
        lw[5][slot] = f2bf(v[8]) | (f2bf(v[9]) << 16);
    }
    __syncthreads();

    // phase 4: coalesced flush (uint2 granularity). Consecutive lanes write
    // consecutive global uint2s within a run; dst recomputed from binId.
    for (int p = tid; p < CHUNK * 3; p += 256) {
        u32 r = (u32)p / 3u;             // magic-mul, compile-time const
        u32 cidx = (u32)p - r * 3u;
        u32 dst = gOff[binId[r]] + r;
        recs[(size_t)dst * 3u + cidx] = make_uint2(lw[2 * cidx][r],
                                                   lw[2 * cidx + 1][r]);
    }
}

// ---- K4 fused: in-LDS cell sort + register gather, one block per tile ----
// Writes 15x15 interior pixels (full sums) with plain stores; 17x17 border
// partials go to borderBuf for k_border to combine. No global atomics.
__global__ void __launch_bounds__(256)
k_fused(const uint2* __restrict__ recs, const u32* __restrict__ binBase,
        const u32* __restrict__ binCnt, float* __restrict__ out,
        float* __restrict__ borderBuf) {
    __shared__ u32 cnt[NBIN];          // histogram -> cursor -> cell end
    __shared__ u32 excl[NBIN];         // cell start
    __shared__ u32 sc[NBIN];           // scan scratch
    __shared__ u32 lrec[CAP * RSTR];   // 43 KB cell-sorted records

    const int tid = threadIdx.x;
    const int g = blockIdx.x;                       // batch*256 + tile
    const int batch = g >> 8, t = g & 255;
    const int ox = (t & 15) * 16, oy = (t >> 4) * 16;
    const u32 base = binBase[g];
    const u32 n = min(binCnt[g], (u32)CAP);         // overflow -> k_cleanup

    cnt[tid] = 0;
    __syncthreads();

    // phase a: stage segment into registers + cell histogram
    u32 r[6][6];
    int cell[6];
#pragma unroll
    for (int k = 0; k < 6; ++k) {
        int i = k * 256 + tid;
        cell[k] = -1;
        if (i < (int)n) {
            size_t sa = (size_t)(base + i) * 3;
            uint2 a = recs[sa], b2 = recs[sa + 1], c2 = recs[sa + 2];
            r[k][0] = a.x;  r[k][1] = a.y;
            r[k][2] = b2.x; r[k][3] = b2.y;
            r[k][4] = c2.x; r[k][5] = c2.y;
            u32 qx = a.x & 0xffffu, qy = a.x >> 16;
            cell[k] = (int)(((qy >> 11) << 4) | (qx >> 11));
            atomicAdd(&cnt[cell[k]], 1u);
        }
    }
    __syncthreads();

    // phase b: exclusive scan of 256 cell counts
    u32 c = cnt[tid];
    sc[tid] = c;
    __syncthreads();
    for (int off = 1; off < 256; off <<= 1) {
        u32 y = (tid >= off) ? sc[tid - off] : 0;
        __syncthreads();
        sc[tid] += y;
        __syncthreads();
    }
    excl[tid] = sc[tid] - c;
    __syncthreads();
    cnt[tid] = excl[tid];                            // cursor
    __syncthreads();

    // phase c: scatter registers into LDS in cell order
#pragma unroll
    for (int k = 0; k < 6; ++k) {
        if (cell[k] >= 0) {
            u32 o = atomicAdd(&cnt[cell[k]], 1u) * RSTR;
#pragma unroll
            for (int w = 0; w < 6; ++w) lrec[o + w] = r[k][w];
        }
    }
    __syncthreads();                                 // cnt[c] is now cell end

    // phase d: gather 17x17 pixel partials from LDS
    for (int p = tid; p < 289; p += 256) {
        int lx = p % 17, ly = p / 17;
        float acc[NC_];
#pragma unroll
        for (int q = 0; q < NC_; ++q) acc[q] = 0.0f;
#pragma unroll
        for (int dy = 0; dy < 2; ++dy) {
            int cy = ly - 1 + dy;                    // dy=1 -> own cell (w=1-ry)
            if ((unsigned)cy >= 16u) continue;
#pragma unroll
            for (int dx = 0; dx < 2; ++dx) {
                int cx = lx - 1 + dx;
                if ((unsigned)cx >= 16u) continue;
                int cc = (cy << 4) | cx;
                u32 j1 = cnt[cc];
                for (u32 j = excl[cc]; j < j1; ++j) {
                    u32 o = j * RSTR;
                    u32 w0 = lrec[o];
                    float rx = (float)(w0 & 2047u)         * (1.0f / 2048.0f);
                    float ry = (float)((w0 >> 16) & 2047u) * (1.0f / 2048.0f);
                    float w = (dx ? (1.0f - rx) : rx) * (dy ? (1.0f - ry) : ry);
                    u32 w1 = lrec[o + 1], w2 = lrec[o + 2], w3 = lrec[o + 3],
                        w4 = lrec[o + 4], w5 = lrec[o + 5];
                    acc[0] += w * bf2f(w1 & 0xffffu); acc[1] += w * bf2f(w1 >> 16);
                    acc[2] += w * bf2f(w2 & 0xffffu); acc[3] += w * bf2f(w2 >> 16);
                    acc[4] += w * bf2f(w3 & 0xffffu); acc[5] += w * bf2f(w3 >> 16);
                    acc[6] += w * bf2f(w4 & 0xffffu); acc[7] += w * bf2f(w4 >> 16);
                    acc[8] += w * bf2f(w5 & 0xffffu); acc[9] += w * bf2f(w5 >> 16);
                }
            }
        }
        bool interior = (lx >= 1) & (lx <= 15) & (ly >= 1) & (ly <= 15);
        if (interior) {
            int gx = ox + lx, gy = oy + ly;
            float* ob = out + (size_t)batch * NC_ * S_ * S_ + gy * S_ + gx;
#pragma unroll
            for (int q = 0; q < NC_; ++q) ob[(size_t)q * S_ * S_] = acc[q];
        } else {
            float* bb = borderBuf + ((size_t)g * 289 + p) * NC_;
#pragma unroll
            for (int q = 0; q < NC_; ++q) bb[q] = acc[q];
        }
    }
}

// ---- K5: combine border partials (<=2x2 tiles per border pixel) ----
// Compact enumeration: 7936 border px per batch (16 cols x 256 + 16 rows x 240)
// instead of launching all 65536 and exiting 88% of threads.
__global__ void __launch_bounds__(256)
k_border(const float* __restrict__ borderBuf, float* __restrict__ out, int total) {
    int idx = blockIdx.x * 256 + threadIdx.x;
    if (idx >= total) return;
    int b = idx / 7936;
    int j = idx - b * 7936;
    int gx, gy;
    if (j < 4096) {                                  // vertical lines gx%16==0
        gx = (j >> 8) << 4;
        gy = j & 255;
    } else {                                         // horizontal, gx%16!=0
        int j2 = j - 4096;
        int row = j2 / 240, col = j2 - row * 240;
        gy = row << 4;
        gx = col + 1 + col / 15;                     // 0..239 -> 1..255 \ {16k}
    }

    int txs[2], lxs[2], nx = 0;
    bool bx = (gx & 15) == 0, by = (gy & 15) == 0;
    if (bx) {
        if (gx > 0) { txs[nx] = (gx >> 4) - 1; lxs[nx] = 16; ++nx; }
        txs[nx] = gx >> 4; lxs[nx] = 0; ++nx;
    } else { txs[0] = gx >> 4; lxs[0] = gx & 15; nx = 1; }
    int tys[2], lys[2], ny = 0;
    if (by) {
        if (gy > 0) { tys[ny] = (gy >> 4) - 1; lys[ny] = 16; ++ny; }
        tys[ny] = gy >> 4; lys[ny] = 0; ++ny;
    } else { tys[0] = gy >> 4; lys[0] = gy & 15; ny = 1; }

    float acc[NC_];
#pragma unroll
    for (int q = 0; q < NC_; ++q) acc[q] = 0.0f;
    for (int jj = 0; jj < ny; ++jj)
        for (int ii = 0; ii < nx; ++ii) {
            int g = (b << 8) + (tys[jj] << 4) + txs[ii];
            int p = lys[jj] * 17 + lxs[ii];
            const float* bb = borderBuf + ((size_t)g * 289 + p) * NC_;
#pragma unroll
            for (int q = 0; q < NC_; ++q) acc[q] += bb[q];
        }
    float* ob = out + (size_t)b * NC_ * S_ * S_ + gy * S_ + gx;
#pragma unroll
    for (int q = 0; q < NC_; ++q) ob[(size_t)q * S_ * S_] = acc[q];
}

// ---- K6: overflow cleanup (normally a no-op; strict correctness) ----
__global__ void __launch_bounds__(256)
k_cleanup(const uint2* __restrict__ recs, const u32* __restrict__ binBase,
          const u32* __restrict__ binCnt, float* __restrict__ out, int nTiles) {
    int g = blockIdx.x * 256 + threadIdx.x;
    if (g >= nTiles) return;
    u32 n = binCnt[g];
    if (n <= (u32)CAP) return;
    int batch = g >> 8, t = g & 255;
    int ox = (t & 15) * 16, oy = (t >> 4) * 16;
    u32 base = binBase[g];
    float* ob = out + (size_t)batch * NC_ * S_ * S_;
    for (u32 i = CAP; i < n; ++i) {
        size_t sa = (size_t)(base + i) * 3;
        uint2 a = recs[sa], b2 = recs[sa + 1], c2 = recs[sa + 2];
        u32 qx = a.x & 0xffffu, qy = a.x >> 16;
        int xi = ox + (int)(qx >> 11), yi = oy + (int)(qy >> 11);
        float rx = (float)(qx & 2047u) * (1.0f / 2048.0f);
        float ry = (float)(qy & 2047u) * (1.0f / 2048.0f);
        float v[NC_];
        v[0] = bf2f(a.y & 0xffffu);  v[1] = bf2f(a.y >> 16);
        v[2] = bf2f(b2.x & 0xffffu); v[3] = bf2f(b2.x >> 16);
        v[4] = bf2f(b2.y & 0xffffu); v[5] = bf2f(b2.y >> 16);
        v[6] = bf2f(c2.x & 0xffffu); v[7] = bf2f(c2.x >> 16);
        v[8] = bf2f(c2.y & 0xffffu); v[9] = bf2f(c2.y >> 16);
        for (int dx = 0; dx < 2; ++dx) {
            int x_ = xi + dx; if (x_ >= S_) continue;
            float wx = dx ? rx : (1.0f - rx);
            for (int dy = 0; dy < 2; ++dy) {
                int y_ = yi + dy; if (y_ >= S_) continue;
                float w = wx * (dy ? ry : (1.0f - ry));
                for (int c = 0; c < NC_; ++c)
                    atomicAdd(ob + (size_t)c * S_ * S_ + y_ * S_ + x_, w * v[c]);
            }
        }
    }
}

// ---- fallback: direct atomic scatter (any shape) ----
__global__ void __launch_bounds__(256)
scatter_cic_kernel(const float* __restrict__ points,
                   const float* __restrict__ values,
                   float* __restrict__ out, int N) {
    const int n = blockIdx.x * blockDim.x + threadIdx.x;
    const int b = blockIdx.y;
    if (n >= N) return;
    const float* pb = points + (size_t)b * 2 * N;
    const float px = (pb[n] + 0.5f) * (float)S_;
    const float py = (pb[(size_t)N + n] + 0.5f) * (float)S_;
    const float xf = floorf(px), yf = floorf(py);
    const float rx = px - xf, ry = py - yf;
    const int xi = (int)xf, yi = (int)yf;
    const float* vb = values + (size_t)b * NC_ * N + n;
    float v[NC_];
#pragma unroll
    for (int c = 0; c < NC_; ++c) v[c] = vb[(size_t)c * N];
    float* ob = out + (size_t)b * NC_ * S_ * S_;
#pragma unroll
    for (int dx = 0; dx < 2; ++dx) {
        const int x_ = xi + dx;
        if (x_ < 0 || x_ >= S_) continue;
        const float wx = dx ? rx : (1.0f - rx);
#pragma unroll
        for (int dy = 0; dy < 2; ++dy) {
            const int y_ = yi + dy;
            if (y_ < 0 || y_ >= S_) continue;
            const float w = wx * (dy ? ry : (1.0f - ry));
            const int idx = y_ * S_ + x_;
#pragma unroll
            for (int c = 0; c < NC_; ++c)
                atomicAdd(ob + (size_t)c * S_ * S_ + idx, w * v[c]);
        }
    }
}

extern "C" void kernel_launch(void* const* d_in, const int* in_sizes, int n_in,
                              void* d_out, int out_size, void* d_ws, size_t ws_size,
                              hipStream_t stream) {
    const float* points = (const float*)d_in[0];   // [B, 2, N]
    const float* values = (const float*)d_in[1];   // [B, NC, N]
    float* out = (float*)d_out;                    // [B, NC, S, S]

    const int B = out_size / (NC_ * S_ * S_);      // 16
    const int N = in_sizes[0] / (2 * B);           // 262144

    const size_t P = (size_t)B * N;
    const int cpb = N / CHUNK;                     // 256
    const int chunksTotal = B * cpb;               // 4096
    const int nTiles = B * NBIN;                   // 4096

    const size_t recBytes    = P * 24;             // 100.7 MB
    const size_t histElems   = (size_t)chunksTotal * NBIN;
    const size_t borderElems = (size_t)nTiles * 289 * NC_;
    const size_t wsNeeded    = recBytes + 2 * histElems * 4 +
                               2 * (size_t)nTiles * 4 + borderElems * 4 + 256;

    const bool fast = (N % CHUNK == 0) && (N >= CHUNK) && (B > 0) &&
                      (P < (1u << 31) / 2) && (ws_size >= wsNeeded);

    if (fast) {
        char* w = (char*)d_ws;
        uint2* recsA     = (uint2*)w;
        u32* hist        = (u32*)(w + recBytes);
        u32* blockStart  = hist + histElems;
        u32* binBase     = blockStart + histElems;
        u32* binCnt      = binBase + nTiles;
        float* borderBuf = (float*)(binCnt + nTiles);

        k_hist<<<chunksTotal, 256, 0, stream>>>(points, hist, N);
        k_scan<<<B, 256, 0, stream>>>(hist, blockStart, binBase, binCnt, cpb, N);
        k_scatter<<<chunksTotal, 256, 0, stream>>>(points, values, blockStart, recsA, N);
        k_fused<<<nTiles, 256, 0, stream>>>(recsA, binBase, binCnt, out, borderBuf);
        const int borderTotal = B * 7936;
        k_border<<<(borderTotal + 255) / 256, 256, 0, stream>>>(borderBuf, out, borderTotal);
        k_cleanup<<<(nTiles + 255) / 256, 256, 0, stream>>>(recsA, binBase, binCnt, out, nTiles);
        // every output pixel is written by k_fused (interior) or k_border -> no memset
    } else {
        hipMemsetAsync(d_out, 0, (size_t)out_size * sizeof(float), stream);
        dim3 block(256, 1, 1);
        dim3 grid((N + 255) / 256, B, 1);
        scatter_cic_kernel<<<grid, block, 0, stream>>>(points, values, out, N);
    }
}

// Round 3
// 389.239 us; speedup vs baseline: 1.1932x; 1.0681x over previous
//
#include <hip/hip_runtime.h>

// Problem constants: BOX=256, OS=1 -> S=256, NC=10, B=16, N=262144
#define S_     256
#define NC_    10
#define CHUNK  1024         // points per staging block (27.7 KB LDS -> 5 blocks/CU)
#define NBIN   256          // 16x16 tiles of 16x16 px per batch
#define CAPR   1536         // record slab per tile (~16 sigma; avg load 1024)
#define CAP    1536         // k_fused LDS record cap (== CAPR: no gap)
#define RSTR   7            // k_fused LDS record stride in u32 (padded)

typedef unsigned int u32;

__device__ __forceinline__ u32 f2bf(float f) {          // f32 -> bf16 (RNE)
    u32 u = __float_as_uint(f);
    return (u + 0x7fffu + ((u >> 16) & 1u)) >> 16;
}
__device__ __forceinline__ float bf2f(u32 h) { return __uint_as_float(h << 16); }

// Record (24 B, 3x uint2): w0 = qx | qy<<16 (tile-local coords, fp 1/2048 px,
// qx in [0,32767]); w1..w5 = 10 bf16 values. cell-in-tile = (qy>>11)*16+(qx>>11).
//
// R3 pipeline: memset(cursor) -> k_scatter (claims slab space with one global
// atomicAdd per non-empty bin per block; no prescan) -> k_fused -> k_border
// (+ overflow cleanup role). k_hist / k_scan / k_cleanup deleted.

// ---- K3: in-LDS counting sort per chunk, then coalesced record flush ----
// R2 lesson: occupancy 18->45% was perf-neutral -> latency chains from 48
// scalar 4B loads/thread at 44 VGPRs were the limiter, not wave count.
// R3: 4 consecutive points/thread -> 12 float4 loads issued at kernel top
// (latency hides under hist+scan+claim); per-record flush.
__global__ void __launch_bounds__(256)
k_scatter(const float* __restrict__ points, const float* __restrict__ values,
          u32* __restrict__ cursor, u32* __restrict__ ovfCnt,
          u32* __restrict__ ovfBuf, uint2* __restrict__ recs, int N) {
    __shared__ u32 cnt[NBIN];           // histogram -> LDS sort cursor
    __shared__ u32 gOff[NBIN];          // global slab base - excl
    __shared__ u32 wsum[4];             // wave partial sums for scan
    __shared__ unsigned char binId[CHUNK];
    __shared__ u32 lw[6][CHUNK];        // 24 KB sorted record words (SoA)

    const int tid = threadIdx.x;
    const int cpb = N / CHUNK;
    const int b  = blockIdx.x / cpb;
    const int n0 = (blockIdx.x % cpb) * CHUNK;
    const float* pb = points + (size_t)b * 2 * N;
    const float* vb = values + (size_t)b * NC_ * N;
    const int nb = n0 + tid * 4;

    cnt[tid] = 0;

    // issue ALL global loads up front (independent; latency hides under the
    // hist/scan/claim phases below)
    const float4 pxv = *(const float4*)(pb + nb);
    const float4 pyv = *(const float4*)(pb + (size_t)N + nb);
    float4 vv[NC_];
#pragma unroll
    for (int c = 0; c < NC_; ++c)
        vv[c] = *(const float4*)(vb + (size_t)c * N + nb);

    __syncthreads();                     // cnt zeroed

    // phase 1: quantize 4 points, per-block bin histogram
    float px4[4] = {pxv.x, pxv.y, pxv.z, pxv.w};
    float py4[4] = {pyv.x, pyv.y, pyv.z, pyv.w};
    u32 w0[4], binA[4];
#pragma unroll
    for (int k = 0; k < 4; ++k) {
        float px = (px4[k] + 0.5f) * (float)S_;
        float py = (py4[k] + 0.5f) * (float)S_;
        int xi = (int)floorf(px), yi = (int)floorf(py);
        u32 qx = __float2uint_rn((px - (float)(xi & ~15)) * 2048.0f);
        u32 qy = __float2uint_rn((py - (float)(yi & ~15)) * 2048.0f);
        qx = min(qx, 32767u); qy = min(qy, 32767u);
        w0[k] = qx | (qy << 16);
        binA[k] = (u32)(((yi >> 4) << 4) + (xi >> 4));
        atomicAdd(&cnt[binA[k]], 1u);
    }
    __syncthreads();

    // phase 2: wave-shfl exclusive scan of 256 bin counts (1 barrier) +
    // global slab claim (one atomic per non-empty bin)
    u32 myCnt = cnt[tid];
    u32 x = myCnt;
#pragma unroll
    for (int off = 1; off < 64; off <<= 1) {
        u32 y = __shfl_up(x, off, 64);
        if ((tid & 63) >= off) x += y;
    }
    if ((tid & 63) == 63) wsum[tid >> 6] = x;
    __syncthreads();
    u32 add = 0;
#pragma unroll
    for (int w = 0; w < 4; ++w) add += (w < (tid >> 6)) ? wsum[w] : 0;
    u32 excl = x - myCnt + add;

    const u32 gt = (u32)b * NBIN + (u32)tid;        // this thread's tile
    u32 gbase = 0;
    if (myCnt) gbase = gt * (u32)CAPR + atomicAdd(&cursor[gt], myCnt);
    gOff[tid] = gbase - excl;
    cnt[tid] = excl;                     // becomes LDS sort cursor
    __syncthreads();

    // phase 3: pack records, scatter into LDS in bin order
#pragma unroll
    for (int k = 0; k < 4; ++k) {
        u32 bin = binA[k];
        u32 slot = atomicAdd(&cnt[bin], 1u);
        binId[slot] = (unsigned char)bin;
#define VG(c) ((&vv[c].x)[k])
        lw[0][slot] = w0[k];
        lw[1][slot] = f2bf(VG(0)) | (f2bf(VG(1)) << 16);
        lw[2][slot] = f2bf(VG(2)) | (f2bf(VG(3)) << 16);
        lw[3][slot] = f2bf(VG(4)) | (f2bf(VG(5)) << 16);
        lw[4][slot] = f2bf(VG(6)) | (f2bf(VG(7)) << 16);
        lw[5][slot] = f2bf(VG(8)) | (f2bf(VG(9)) << 16);
#undef VG
    }
    __syncthreads();

    // phase 4: per-record coalesced flush. Consecutive lanes hold consecutive
    // sorted records -> consecutive 24B global slots within each run.
    const u32 tb0 = (u32)b * NBIN;
#pragma unroll
    for (int k = 0; k < 4; ++k) {
        u32 r = (u32)tid + (u32)k * 256;
        u32 bin = binId[r];
        u32 dst = gOff[bin] + r;
        u32 a0 = lw[0][r], a1 = lw[1][r], a2 = lw[2][r],
            a3 = lw[3][r], a4 = lw[4][r], a5 = lw[5][r];
        u32 rel = dst - (tb0 + bin) * (u32)CAPR;
        if (rel < (u32)CAPR) {           // always true unless tile > CAPR recs
            size_t s3 = (size_t)dst * 3;
            recs[s3]     = make_uint2(a0, a1);
            recs[s3 + 1] = make_uint2(a2, a3);
            recs[s3 + 2] = make_uint2(a4, a5);
        } else {                         // slab overflow -> side list
            u32 oi = atomicAdd(ovfCnt, 1u);
            u32* ob = ovfBuf + (size_t)oi * 7;
            ob[0] = tb0 + bin;
            ob[1] = a0; ob[2] = a1; ob[3] = a2;
            ob[4] = a3; ob[5] = a4; ob[6] = a5;
        }
    }
}

// ---- K4 fused: in-LDS cell sort + register gather, one block per tile ----
// Writes 15x15 interior pixels (full sums) with plain stores; 17x17 border
// partials go to borderBuf for k_border to combine. No global atomics.
__global__ void __launch_bounds__(256)
k_fused(const uint2* __restrict__ recs, const u32* __restrict__ cursor,
        float* __restrict__ out, float* __restrict__ borderBuf) {
    __shared__ u32 cnt[NBIN];          // histogram -> cursor -> cell end
    __shared__ u32 excl[NBIN];         // cell start
    __shared__ u32 wsum[4];
    __shared__ u32 lrec[CAP * RSTR];   // 43 KB cell-sorted records

    const int tid = threadIdx.x;
    const int g = blockIdx.x;                       // batch*256 + tile
    const int batch = g >> 8, t = g & 255;
    const int ox = (t & 15) * 16, oy = (t >> 4) * 16;
    const u32 base = (u32)g * (u32)CAPR;            // fixed slab base
    const u32 n = min(cursor[g], (u32)CAP);         // overflow -> k_border tail

    cnt[tid] = 0;
    __syncthreads();

    // phase a: stage segment into registers + cell histogram
    u32 r[6][6];
    int cell[6];
#pragma unroll
    for (int k = 0; k < 6; ++k) {
        int i = k * 256 + tid;
        cell[k] = -1;
        if (i < (int)n) {
            size_t sa = (size_t)(base + i) * 3;
            uint2 a = recs[sa], b2 = recs[sa + 1], c2 = recs[sa + 2];
            r[k][0] = a.x;  r[k][1] = a.y;
            r[k][2] = b2.x; r[k][3] = b2.y;
            r[k][4] = c2.x; r[k][5] = c2.y;
            u32 qx = a.x & 0xffffu, qy = a.x >> 16;
            cell[k] = (int)(((qy >> 11) << 4) | (qx >> 11));
            atomicAdd(&cnt[cell[k]], 1u);
        }
    }
    __syncthreads();

    // phase b: wave-shfl exclusive scan of 256 cell counts (1 barrier)
    u32 c = cnt[tid];
    u32 x = c;
#pragma unroll
    for (int off = 1; off < 64; off <<= 1) {
        u32 y = __shfl_up(x, off, 64);
        if ((tid & 63) >= off) x += y;
    }
    if ((tid & 63) == 63) wsum[tid >> 6] = x;
    __syncthreads();
    u32 add = 0;
#pragma unroll
    for (int w = 0; w < 4; ++w) add += (w < (tid >> 6)) ? wsum[w] : 0;
    u32 ex = x - c + add;
    excl[tid] = ex;
    cnt[tid] = ex;                                   // cursor
    __syncthreads();

    // phase c: scatter registers into LDS in cell order
#pragma unroll
    for (int k = 0; k < 6; ++k) {
        if (cell[k] >= 0) {
            u32 o = atomicAdd(&cnt[cell[k]], 1u) * RSTR;
#pragma unroll
            for (int w = 0; w < 6; ++w) lrec[o + w] = r[k][w];
        }
    }
    __syncthreads();                                 // cnt[c] is now cell end

    // phase d: gather 17x17 pixel partials from LDS
    for (int p = tid; p < 289; p += 256) {
        int lx = p % 17, ly = p / 17;
        float acc[NC_];
#pragma unroll
        for (int q = 0; q < NC_; ++q) acc[q] = 0.0f;
#pragma unroll
        for (int dy = 0; dy < 2; ++dy) {
            int cy = ly - 1 + dy;                    // dy=1 -> own cell (w=1-ry)
            if ((unsigned)cy >= 16u) continue;
#pragma unroll
            for (int dx = 0; dx < 2; ++dx) {
                int cx = lx - 1 + dx;
                if ((unsigned)cx >= 16u) continue;
                int cc = (cy << 4) | cx;
                u32 j1 = cnt[cc];
                for (u32 j = excl[cc]; j < j1; ++j) {
                    u32 o = j * RSTR;
                    u32 w0 = lrec[o];
                    float rx = (float)(w0 & 2047u)         * (1.0f / 2048.0f);
                    float ry = (float)((w0 >> 16) & 2047u) * (1.0f / 2048.0f);
                    float w = (dx ? (1.0f - rx) : rx) * (dy ? (1.0f - ry) : ry);
                    u32 w1 = lrec[o + 1], w2 = lrec[o + 2], w3 = lrec[o + 3],
                        w4 = lrec[o + 4], w5 = lrec[o + 5];
                    acc[0] += w * bf2f(w1 & 0xffffu); acc[1] += w * bf2f(w1 >> 16);
                    acc[2] += w * bf2f(w2 & 0xffffu); acc[3] += w * bf2f(w2 >> 16);
                    acc[4] += w * bf2f(w3 & 0xffffu); acc[5] += w * bf2f(w3 >> 16);
                    acc[6] += w * bf2f(w4 & 0xffffu); acc[7] += w * bf2f(w4 >> 16);
                    acc[8] += w * bf2f(w5 & 0xffffu); acc[9] += w * bf2f(w5 >> 16);
                }
            }
        }
        bool interior = (lx >= 1) & (lx <= 15) & (ly >= 1) & (ly <= 15);
        if (interior) {
            int gx = ox + lx, gy = oy + ly;
            float* ob = out + (size_t)batch * NC_ * S_ * S_ + gy * S_ + gx;
#pragma unroll
            for (int q = 0; q < NC_; ++q) ob[(size_t)q * S_ * S_] = acc[q];
        } else {
            float* bb = borderBuf + ((size_t)g * 289 + p) * NC_;
#pragma unroll
            for (int q = 0; q < NC_; ++q) bb[q] = acc[q];
        }
    }
}

// ---- K5: combine border partials; tail blocks process slab-overflow list ----
#define CLEAN_T 4096                                 // 16 tail blocks
__global__ void __launch_bounds__(256)
k_border(const float* __restrict__ borderBuf, float* __restrict__ out,
         const u32* __restrict__ ovfCnt, const u32* __restrict__ ovfBuf,
         int total) {
    int idx = blockIdx.x * 256 + threadIdx.x;
    if (idx >= total) {
        // overflow-cleanup role (no-op unless a tile exceeded CAPR records)
        u32 oc = *ovfCnt;
        for (u32 j = (u32)(idx - total); j < oc; j += CLEAN_T) {
            const u32* ob = ovfBuf + (size_t)j * 7;
            u32 g = ob[0];
            int batch = (int)(g >> 8), t = (int)(g & 255u);
            int ox = (t & 15) * 16, oy = (t >> 4) * 16;
            u32 w0 = ob[1];
            u32 qx = w0 & 0xffffu, qy = w0 >> 16;
            int xi = ox + (int)(qx >> 11), yi = oy + (int)(qy >> 11);
            float rx = (float)(qx & 2047u) * (1.0f / 2048.0f);
            float ry = (float)(qy & 2047u) * (1.0f / 2048.0f);
            float v[NC_];
            v[0] = bf2f(ob[2] & 0xffffu); v[1] = bf2f(ob[2] >> 16);
            v[2] = bf2f(ob[3] & 0xffffu); v[3] = bf2f(ob[3] >> 16);
            v[4] = bf2f(ob[4] & 0xffffu); v[5] = bf2f(ob[4] >> 16);
            v[6] = bf2f(ob[5] & 0xffffu); v[7] = bf2f(ob[5] >> 16);
            v[8] = bf2f(ob[6] & 0xffffu); v[9] = bf2f(ob[6] >> 16);
            float* obase = out + (size_t)batch * NC_ * S_ * S_;
            for (int dx = 0; dx < 2; ++dx) {
                int x_ = xi + dx; if (x_ >= S_) continue;
                float wx = dx ? rx : (1.0f - rx);
                for (int dy = 0; dy < 2; ++dy) {
                    int y_ = yi + dy; if (y_ >= S_) continue;
                    float w = wx * (dy ? ry : (1.0f - ry));
                    for (int cc = 0; cc < NC_; ++cc)
                        atomicAdd(obase + (size_t)cc * S_ * S_ + y_ * S_ + x_,
                                  w * v[cc]);
                }
            }
        }
        return;
    }
    int b = idx / 7936;
    int j = idx - b * 7936;
    int gx, gy;
    if (j < 4096) {                                  // vertical lines gx%16==0
        gx = (j >> 8) << 4;
        gy = j & 255;
    } else {                                         // horizontal, gx%16!=0
        int j2 = j - 4096;
        int row = j2 / 240, col = j2 - row * 240;
        gy = row << 4;
        gx = col + 1 + col / 15;                     // 0..239 -> 1..255 \ {16k}
    }

    int txs[2], lxs[2], nx = 0;
    bool bx = (gx & 15) == 0, by = (gy & 15) == 0;
    if (bx) {
        if (gx > 0) { txs[nx] = (gx >> 4) - 1; lxs[nx] = 16; ++nx; }
        txs[nx] = gx >> 4; lxs[nx] = 0; ++nx;
    } else { txs[0] = gx >> 4; lxs[0] = gx & 15; nx = 1; }
    int tys[2], lys[2], ny = 0;
    if (by) {
        if (gy > 0) { tys[ny] = (gy >> 4) - 1; lys[ny] = 16; ++ny; }
        tys[ny] = gy >> 4; lys[ny] = 0; ++ny;
    } else { tys[0] = gy >> 4; lys[0] = gy & 15; ny = 1; }

    float acc[NC_];
#pragma unroll
    for (int q = 0; q < NC_; ++q) acc[q] = 0.0f;
    for (int jj = 0; jj < ny; ++jj)
        for (int ii = 0; ii < nx; ++ii) {
            int g = (b << 8) + (tys[jj] << 4) + txs[ii];
            int p = lys[jj] * 17 + lxs[ii];
            const float* bb = borderBuf + ((size_t)g * 289 + p) * NC_;
#pragma unroll
            for (int q = 0; q < NC_; ++q) acc[q] += bb[q];
        }
    float* ob = out + (size_t)b * NC_ * S_ * S_ + gy * S_ + gx;
#pragma unroll
    for (int q = 0; q < NC_; ++q) ob[(size_t)q * S_ * S_] = acc[q];
}

// ---- fallback: direct atomic scatter (any shape) ----
__global__ void __launch_bounds__(256)
scatter_cic_kernel(const float* __restrict__ points,
                   const float* __restrict__ values,
                   float* __restrict__ out, int N) {
    const int n = blockIdx.x * blockDim.x + threadIdx.x;
    const int b = blockIdx.y;
    if (n >= N) return;
    const float* pb = points + (size_t)b * 2 * N;
    const float px = (pb[n] + 0.5f) * (float)S_;
    const float py = (pb[(size_t)N + n] + 0.5f) * (float)S_;
    const float xf = floorf(px), yf = floorf(py);
    const float rx = px - xf, ry = py - yf;
    const int xi = (int)xf, yi = (int)yf;
    const float* vb = values + (size_t)b * NC_ * N + n;
    float v[NC_];
#pragma unroll
    for (int c = 0; c < NC_; ++c) v[c] = vb[(size_t)c * N];
    float* ob = out + (size_t)b * NC_ * S_ * S_;
#pragma unroll
    for (int dx = 0; dx < 2; ++dx) {
        const int x_ = xi + dx;
        if (x_ < 0 || x_ >= S_) continue;
        const float wx = dx ? rx : (1.0f - rx);
#pragma unroll
        for (int dy = 0; dy < 2; ++dy) {
            const int y_ = yi + dy;
            if (y_ < 0 || y_ >= S_) continue;
            const float w = wx * (dy ? ry : (1.0f - ry));
            const int idx = y_ * S_ + x_;
#pragma unroll
            for (int c = 0; c < NC_; ++c)
                atomicAdd(ob + (size_t)c * S_ * S_ + idx, w * v[c]);
        }
    }
}

extern "C" void kernel_launch(void* const* d_in, const int* in_sizes, int n_in,
                              void* d_out, int out_size, void* d_ws, size_t ws_size,
                              hipStream_t stream) {
    const float* points = (const float*)d_in[0];   // [B, 2, N]
    const float* values = (const float*)d_in[1];   // [B, NC, N]
    float* out = (float*)d_out;                    // [B, NC, S, S]

    const int B = out_size / (NC_ * S_ * S_);      // 16
    const int N = in_sizes[0] / (2 * B);           // 262144

    const size_t P = (size_t)B * N;
    const int cpb = N / CHUNK;                     // 256
    const int chunksTotal = B * cpb;               // 4096
    const int nTiles = B * NBIN;                   // 4096

    const size_t recBytes    = (size_t)nTiles * CAPR * 24;   // 151.0 MB slabs
    const size_t borderElems = (size_t)nTiles * 289 * NC_;
    const size_t ovfBytes    = P * 7 * 4;          // worst-case overflow list
    const size_t wsNeeded    = recBytes + (size_t)(nTiles + 1) * 4 +
                               borderElems * 4 + ovfBytes + 256;

    const bool fast = (N % CHUNK == 0) && (N >= CHUNK) && (B > 0) &&
                      (P < (1u << 31) / 2) && (ws_size >= wsNeeded);

    if (fast) {
        char* w = (char*)d_ws;
        uint2* recsA     = (uint2*)w;
        u32* cursor      = (u32*)(w + recBytes);   // nTiles counters
        u32* ovfCnt      = cursor + nTiles;        // +1 overflow counter
        float* borderBuf = (float*)(ovfCnt + 1);
        u32* ovfBuf      = (u32*)(borderBuf + borderElems);

        hipMemsetAsync(cursor, 0, (size_t)(nTiles + 1) * 4, stream);
        k_scatter<<<chunksTotal, 256, 0, stream>>>(points, values, cursor,
                                                   ovfCnt, ovfBuf, recsA, N);
        k_fused<<<nTiles, 256, 0, stream>>>(recsA, cursor, out, borderBuf);
        const int borderTotal = B * 7936;
        k_border<<<borderTotal / 256 + CLEAN_T / 256, 256, 0, stream>>>(
            borderBuf, out, ovfCnt, ovfBuf, borderTotal);
        // every output pixel is written by k_fused (interior) or k_border
    } else {
        hipMemsetAsync(d_out, 0, (size_t)out_size * sizeof(float), stream);
        dim3 block(256, 1, 1);
        dim3 grid((N + 255) / 256, B, 1);
        scatter_cic_kernel<<<grid, block, 0, stream>>>(points, values, out, N);
    }
}